// Round 11
// baseline (216.395 us; speedup 1.0000x reference)
//
#include <hip/hip_runtime.h>

// ---------------------------------------------------------------------------
// PEPS 4x5, D=4, P=2, depth-5 gate sweeps, 64-point gather.
// Gate layout: psi idx = c3<<16 | c4<<12 | c0<<8 | c1<<4 | c2,
// nibble c_j = column j, nibble bit (3-i) = row i.
//   P1: G2_01, G2_12, M16_0, M16_1   (slab = low 12 bits, contiguous)
//   P2: G2_23, G2_34, M16_2..4       (slab = bits {19..12,3..0}, 64B runs)
// Rounds are wave-paired: pair partner's inputs are produced by lanes of the
// same wave (wave bits = shared free bits), so intra-pair sync is a wave-level
// fence instead of __syncthreads. Barriers: P1 7->4, P2 8->5.
// ---------------------------------------------------------------------------

#define PAD(i) ((i) + (((i) >> 4) << 2))   // +4 floats per 16 -> LDS bank spread
#define PIDX(i,j,p,u,d,l,r) (((((((i)*5+(j))*2+(p))*4+(u))*4+(d))*4+(l))*4+(r))
#define WSYNC() do { asm volatile("s_waitcnt lgkmcnt(0)" ::: "memory"); \
                     __builtin_amdgcn_wave_barrier(); } while (0)

// workspace float offsets
static constexpr int COL0  = 0;                    // [16][256]
static constexpr int COL1  = 4096;                 // [16][256][256]
static constexpr int COL2  = COL1 + 1048576;
static constexpr int COL3  = COL2 + 1048576;
static constexpr int COL4  = COL3 + 1048576;       // [16][256]
static constexpr int M01TO = COL4 + 4096;          // [c01=256][R2=256]
static constexpr int M34TO = M01TO + 65536;        // [L3=256][c34=256]
static constexpr int T12TO = M34TO + 65536;        // [c2=16][c01=256][R3=256]
static constexpr int PSIO  = T12TO + 1048576;      // [2^20] gate layout

// --------------------------- column tensors --------------------------------
__global__ __launch_bounds__(256) void k_build_cols(const float* __restrict__ peps,
                                                    float* __restrict__ ws) {
  __shared__ float p01[4096], p23[4096];
  int bid = blockIdx.x, t = threadIdx.x;
  if (bid < 384) {
    int col = 1 + (bid >> 7);
    int part = bid & 127;
#pragma unroll
    for (int k = 0; k < 16; ++k) {
      int e = k * 256 + t;
      int r12 = e & 15, l12 = (e >> 4) & 15, d2 = (e >> 8) & 3, p = e >> 10;
      int l1 = l12 >> 2, l2 = l12 & 3, r1 = r12 >> 2, r2 = r12 & 3;
      float s01 = 0.f, s23 = 0.f;
#pragma unroll
      for (int d = 0; d < 4; ++d) {
        s01 += peps[PIDX(0, col, (p >> 1), 0, d, l1, r1)] *
               peps[PIDX(1, col, (p & 1), d, d2, l2, r2)];
        s23 += peps[PIDX(2, col, (p >> 1), d2, d, l1, r1)] *
               peps[PIDX(3, col, (p & 1), d, 0, l2, r2)];
      }
      p01[e] = s01;
      p23[e] = s23;
    }
    __syncthreads();
    const int coloffs[3] = {COL1, COL2, COL3};
    float* out = ws + coloffs[col - 1];
#pragma unroll
    for (int k = 0; k < 8; ++k) {
      int eq = part * 8192 + (k * 256 + t) * 4;
      int r34b = eq & 15;
      int r12 = (eq >> 4) & 15, l34 = (eq >> 8) & 15, l12 = (eq >> 12) & 15;
      int p = eq >> 16;
      int pa = p >> 2, pb = p & 3;
      float4 acc = {0.f, 0.f, 0.f, 0.f};
#pragma unroll
      for (int d2 = 0; d2 < 4; ++d2) {
        float a01 = p01[((((pa * 4 + d2) << 4) | l12) << 4) | r12];
        const float4 b4 =
            *(const float4*)&p23[((((pb * 4 + d2) << 4) | l34) << 4) | r34b];
        acc.x += a01 * b4.x;
        acc.y += a01 * b4.y;
        acc.z += a01 * b4.z;
        acc.w += a01 * b4.w;
      }
      *(float4*)&out[eq] = acc;
    }
  } else {
    int col = (bid == 384) ? 0 : 4;
    const int lsh = (col == 0) ? 0 : 2;
    const int rsh = (col == 4) ? 0 : 2;
    const int ldim = 1 << lsh, rdim = 1 << rsh;
    const int LLB = 2 * lsh, RRB = 2 * rsh;
    const int LL = 1 << LLB, RR = 1 << RRB;
    int n12 = (LL * RR) << 4;
    for (int e = t; e < n12; e += 256) {
      int r12 = e & (RR - 1);
      int l12 = (e >> RRB) & (LL - 1);
      int d2 = (e >> (RRB + LLB)) & 3;
      int p = e >> (RRB + LLB + 2);
      int l1 = l12 >> lsh, l2 = l12 & (ldim - 1);
      int r1 = r12 >> rsh, r2 = r12 & (rdim - 1);
      float s01 = 0.f, s23 = 0.f;
      for (int d = 0; d < 4; ++d) {
        s01 += peps[PIDX(0, col, (p >> 1), 0, d, l1, r1)] *
               peps[PIDX(1, col, (p & 1), d, d2, l2, r2)];
        s23 += peps[PIDX(2, col, (p >> 1), d2, d, l1, r1)] *
               peps[PIDX(3, col, (p & 1), d, 0, l2, r2)];
      }
      p01[e] = s01;
      p23[e] = s23;
    }
    __syncthreads();
    const int LB = 2 * LLB, RB = 2 * RRB;
    int total = 16 << (LB + RB);  // 4096
    float* out = ws + ((col == 0) ? COL0 : COL4);
    for (int e = t; e < total; e += 256) {
      int r = e & ((1 << RB) - 1);
      int l = (e >> RB) & ((1 << LB) - 1);
      int p = e >> (RB + LB);
      int r34 = r & (RR - 1), r12 = r >> RRB;
      int l34 = l & (LL - 1), l12 = l >> LLB;
      int pa = p >> 2, pb = p & 3;
      float s = 0.f;
      for (int d2 = 0; d2 < 4; ++d2) {
        s += p01[((((pa * 4 + d2) << LLB) | l12) << RRB) | r12] *
             p23[((((pb * 4 + d2) << LLB) | l34) << RRB) | r34];
      }
      out[e] = s;
    }
  }
}

// ------------------- M01 / M34T (edge-pair contractions) -------------------
__global__ __launch_bounds__(256) void k_small(const float* __restrict__ ws,
                                               float* __restrict__ m01,
                                               float* __restrict__ m34t) {
  __shared__ float c3buf[4112], c4buf[4112];
  int t = threadIdx.x;
  if (blockIdx.x < 64) {
    int c1 = blockIdx.x >> 2, q = blockIdx.x & 3;
    int r2l = t & 63, c0g = t >> 6;  // wave-uniform c0 group (4 c0 each)
    int R2 = q * 64 + r2l;
    const float* col0 = ws + COL0;
    const float* col1 = ws + COL1;
    float a0 = 0.f, a1 = 0.f, a2 = 0.f, a3 = 0.f;
    for (int R1 = 0; R1 < 256; ++R1) {
      float bv = col1[(c1 * 256 + R1) * 256 + R2];  // coalesced
      a0 += col0[(c0g * 4 + 0) * 256 + R1] * bv;    // uniform -> s_load
      a1 += col0[(c0g * 4 + 1) * 256 + R1] * bv;
      a2 += col0[(c0g * 4 + 2) * 256 + R1] * bv;
      a3 += col0[(c0g * 4 + 3) * 256 + R1] * bv;
    }
    m01[((c0g * 4 + 0) * 16 + c1) * 256 + R2] = a0;  // coalesced
    m01[((c0g * 4 + 1) * 16 + c1) * 256 + R2] = a1;
    m01[((c0g * 4 + 2) * 16 + c1) * 256 + R2] = a2;
    m01[((c0g * 4 + 3) * 16 + c1) * 256 + R2] = a3;
  } else {
    int L3 = blockIdx.x - 64;  // 0..255
    const float* col3 = ws + COL3;
    const float* col4 = ws + COL4;
    for (int e = t; e < 4096; e += 256) {
      c4buf[(e >> 8) * 257 + (e & 255)] = col4[e];
      c3buf[(e >> 8) * 257 + (e & 255)] =
          col3[(e >> 8) * 65536 + L3 * 256 + (e & 255)];
    }
    __syncthreads();
    int c3 = t >> 4, c4 = t & 15;
    float acc = 0.f;
    for (int B = 0; B < 256; ++B)
      acc += c3buf[c3 * 257 + B] * c4buf[c4 * 257 + B];
    m34t[L3 * 256 + t] = acc;
  }
}

// ---------------- T012[c2][c01][R3] = M01 x Col2 ---------------------------
__global__ __launch_bounds__(256) void k_t012(const float* __restrict__ m01,
                                              const float* __restrict__ col2,
                                              float* __restrict__ t012) {
  __shared__ float A[4096];  // [i=16][R2=256]
  int t = threadIdx.x;       // R3
  int c2 = blockIdx.x & 15, tg = blockIdx.x >> 4;
#pragma unroll
  for (int k = 0; k < 4; ++k)
    *(float4*)&A[(k * 256 + t) * 4] =
        *(const float4*)&m01[tg * 4096 + (k * 256 + t) * 4];
  __syncthreads();
  float acc[16] = {};
  for (int R2 = 0; R2 < 256; R2 += 4) {
    float b0 = col2[c2 * 65536 + (R2 + 0) * 256 + t];
    float b1 = col2[c2 * 65536 + (R2 + 1) * 256 + t];
    float b2 = col2[c2 * 65536 + (R2 + 2) * 256 + t];
    float b3 = col2[c2 * 65536 + (R2 + 3) * 256 + t];
#pragma unroll
    for (int i = 0; i < 16; ++i) {
      float4 a4 = *(const float4*)&A[i * 256 + R2];  // broadcast b128
      acc[i] += a4.x * b0 + a4.y * b1 + a4.z * b2 + a4.w * b3;
    }
  }
#pragma unroll
  for (int i = 0; i < 16; ++i)
    t012[c2 * 65536 + (tg * 16 + i) * 256 + t] = acc[i];  // coalesced
}

// ---------------- psi = T012 x M34T, emitted in GATE layout ----------------
__global__ __launch_bounds__(256) void k_psi0(const float* __restrict__ t012,
                                              const float* __restrict__ m34t,
                                              float* __restrict__ psi) {
  __shared__ float A[4096];  // [i=c2=16][L3=256]
  __shared__ float S[4112];  // [c2=16][c34=257-padded]
  int t = threadIdx.x;       // c34 (and L3 for staging)
  int tg = blockIdx.x;       // c01
#pragma unroll
  for (int i = 0; i < 16; ++i)
    A[i * 256 + t] = t012[i * 65536 + tg * 256 + t];  // coalesced 1KB chunks
  __syncthreads();
  float acc[16] = {};
  for (int L3 = 0; L3 < 256; L3 += 4) {
    float b0 = m34t[(L3 + 0) * 256 + t];
    float b1 = m34t[(L3 + 1) * 256 + t];
    float b2 = m34t[(L3 + 2) * 256 + t];
    float b3 = m34t[(L3 + 3) * 256 + t];
#pragma unroll
    for (int i = 0; i < 16; ++i) {
      float4 a4 = *(const float4*)&A[i * 256 + L3];  // broadcast b128
      acc[i] += a4.x * b0 + a4.y * b1 + a4.z * b2 + a4.w * b3;
    }
  }
#pragma unroll
  for (int i = 0; i < 16; ++i) S[i * 257 + t] = acc[i];
  __syncthreads();
  // store: u = c3*16 + c2, v = c4 -> 64B runs (c2 lane-consecutive)
  int c3 = t >> 4, c2 = t & 15;
  int base = c3 * 65536 + (tg >> 4) * 256 + (tg & 15) * 16 + c2;
#pragma unroll
  for (int v = 0; v < 16; ++v)
    psi[base + v * 4096] = S[c2 * 257 + c3 * 16 + v];
}

// ---------------- register-level 2-qubit gate ------------------------------
template <int NB, int HI, int LO>
__device__ __forceinline__ void gate2(float* x, const float* __restrict__ g) {
  constexpr int H = 1 << HI, L = 1 << LO, N = 1 << NB;
#pragma unroll
  for (int o = 0; o < N; ++o) {
    if (o & (H | L)) continue;
    float v0 = x[o], v1 = x[o + L], v2 = x[o + H], v3 = x[o + H + L];
    x[o]         = g[0]  * v0 + g[1]  * v1 + g[2]  * v2 + g[3]  * v3;
    x[o + L]     = g[4]  * v0 + g[5]  * v1 + g[6]  * v2 + g[7]  * v3;
    x[o + H]     = g[8]  * v0 + g[9]  * v1 + g[10] * v2 + g[11] * v3;
    x[o + H + L] = g[12] * v0 + g[13] * v1 + g[14] * v2 + g[15] * v3;
  }
}

// V column transform: 4-bit nibble, x bit3 = row 0; bonds (3,2),(2,1),(1,0)
template <int ST>
__device__ __forceinline__ void vxf(float* s, const float* __restrict__ g, int b) {
  float x[16];
#pragma unroll
  for (int m = 0; m < 16; ++m) x[m] = s[PAD(b + m * ST)];
  gate2<4, 3, 2>(x, g);
  gate2<4, 2, 1>(x, g);
  gate2<4, 1, 0>(x, g);
#pragma unroll
  for (int m = 0; m < 16; ++m) s[PAD(b + m * ST)] = x[m];
}

// Bond pair at explicit base: gate(B2,B1) then gate(B1,B0) on an 8-elem group.
template <int B2, int B1, int B0>
__device__ __forceinline__ void bp_at(float* s, const float* __restrict__ g,
                                      int b) {
  float x[8];
#pragma unroll
  for (int m = 0; m < 8; ++m) {
    int off = ((m >> 2) & 1) * (1 << B2) + ((m >> 1) & 1) * (1 << B1) +
              (m & 1) * (1 << B0);
    x[m] = s[PAD(b + off)];
  }
  gate2<3, 2, 1>(x, g);
  gate2<3, 1, 0>(x, g);
#pragma unroll
  for (int m = 0; m < 8; ++m) {
    int off = ((m >> 2) & 1) * (1 << B2) + ((m >> 1) & 1) * (1 << B1) +
              (m & 1) * (1 << B0);
    s[PAD(b + off)] = x[m];
  }
}

// Wave-pair shared-base helpers.
// Pair A (triples {8,4,0}/{9,5,1} or {0,8,4}/{1,9,5}): shared {11,10,7 | 6,3,2}
__device__ __forceinline__ int shA(int w, int l) {
  return ((w >> 2) & 1) * 2048 + ((w >> 1) & 1) * 1024 + (w & 1) * 128 +
         ((l >> 5) & 1) * 64 + ((l >> 4) & 1) * 8 + ((l >> 3) & 1) * 4;
}
// Pair B (triples {10,6,2}/{11,7,3} etc.): shared {9,8,5 | 4,1,0}
__device__ __forceinline__ int shB(int w, int l) {
  return ((w >> 2) & 1) * 512 + ((w >> 1) & 1) * 256 + (w & 1) * 32 +
         ((l >> 5) & 1) * 16 + ((l >> 4) & 1) * 2 + ((l >> 3) & 1) * 1;
}
__device__ __forceinline__ int fb951(int l) {  // bits {9,5,1}
  return ((l >> 2) & 1) * 512 + ((l >> 1) & 1) * 32 + (l & 1) * 2;
}
__device__ __forceinline__ int fb840(int l) {  // bits {8,4,0}
  return ((l >> 2) & 1) * 256 + ((l >> 1) & 1) * 16 + (l & 1) * 1;
}
__device__ __forceinline__ int fb1173(int l) {  // bits {11,7,3}
  return ((l >> 2) & 1) * 2048 + ((l >> 1) & 1) * 128 + (l & 1) * 8;
}
__device__ __forceinline__ int fb1062(int l) {  // bits {10,6,2}
  return ((l >> 2) & 1) * 1024 + ((l >> 1) & 1) * 64 + (l & 1) * 4;
}

// Phase P1: G2_01, G2_12 (rows 0..3), M16_0, M16_1.
// slab local: c0 = bits 11..8, c1 = 7..4, c2 = 3..0; outer o = (c3,c4).
__global__ __launch_bounds__(512) void k_P1(float* __restrict__ psi,
                                            const float* __restrict__ gate) {
  __shared__ float s[5120];
  float g[16];
#pragma unroll
  for (int i = 0; i < 16; ++i) g[i] = gate[i];
  int t = threadIdx.x;  // 512
  int o = blockIdx.x;
  int w = t >> 6, l = t & 63;
#pragma unroll
  for (int i = 0; i < 2; ++i) {
    int f = (i * 512 + t) * 4;
    *(float4*)(s + PAD(f)) = *(const float4*)(psi + o * 4096 + f);
  }
  __syncthreads();
  {  // pair: rows 0,1 — wave owns slab bits {11,10,7}
    int sh = shA(w, l);
    bp_at<8, 4, 0>(s, g, sh + fb951(l));
    WSYNC();
    bp_at<9, 5, 1>(s, g, sh + fb840(l));
  }
  __syncthreads();
  {  // pair: rows 2,3 — wave owns slab bits {9,8,5}
    int sh = shB(w, l);
    bp_at<10, 6, 2>(s, g, sh + fb1173(l));
    WSYNC();
    bp_at<11, 7, 3>(s, g, sh + fb1062(l));
  }
  __syncthreads();
  if (t < 256) {  // pair: M16_0, M16_1 — wave owns slab bits {1,0}
    int w2 = (t >> 6) & 3, l6 = t & 63;
    vxf<256>(s, g, (l6 << 2) | w2);                               // M16_0
    WSYNC();
    vxf<16>(s, g, (((l6 >> 2) & 15) << 8) | ((l6 & 3) << 2) | w2); // M16_1
  }
  __syncthreads();
#pragma unroll
  for (int i = 0; i < 2; ++i) {
    int f = (i * 512 + t) * 4;
    *(float4*)(psi + o * 4096 + f) = *(const float4*)(s + PAD(f));
  }
}

// Phase P2: G2_23, G2_34 (rows 0..3), M16_2, M16_3, M16_4.
// slab local: c3 = bits 11..8, c4 = 7..4, c2 = 3..0; outer o = (c0,c1).
template <bool LAST>
__global__ __launch_bounds__(512) void k_P2(float* __restrict__ psi,
                                            const float* __restrict__ gate,
                                            const int* __restrict__ x,
                                            float* __restrict__ out) {
  __shared__ float s[5120];
  float g[16];
#pragma unroll
  for (int i = 0; i < 16; ++i) g[i] = gate[i];
  int t = threadIdx.x;  // 512
  int o = blockIdx.x;
  int w = t >> 6, l = t & 63;
#pragma unroll
  for (int i = 0; i < 2; ++i) {
    int f = (i * 512 + t) * 4;
    int addr = (f >> 8) * 65536 + ((f >> 4) & 15) * 4096 + o * 16 + (f & 15);
    *(float4*)(s + PAD(f)) = *(const float4*)(psi + addr);
  }
  __syncthreads();
  {  // pair: rows 0,1 — wave owns slab bits {11,10,7}
    int sh = shA(w, l);
    bp_at<0, 8, 4>(s, g, sh + fb951(l));
    WSYNC();
    bp_at<1, 9, 5>(s, g, sh + fb840(l));
  }
  __syncthreads();
  {  // pair: rows 2,3 — wave owns slab bits {9,8,5}
    int sh = shB(w, l);
    bp_at<2, 10, 6>(s, g, sh + fb1173(l));
    WSYNC();
    bp_at<3, 11, 7>(s, g, sh + fb1062(l));
  }
  __syncthreads();
  if (t < 256) {  // pair: M16_2, M16_3 — wave owns slab bits {5,4}
    int w2 = (t >> 6) & 3, l6 = t & 63;
    vxf<1>(s, g, (l6 << 6) | (w2 << 4));                               // M16_2
    WSYNC();
    vxf<256>(s, g, (((l6 >> 4) & 3) << 6) | (w2 << 4) | (l6 & 15));    // M16_3
  }
  __syncthreads();
  if (t < 256) vxf<16>(s, g, ((t >> 4) << 8) | (t & 15));              // M16_4
  __syncthreads();
  if (LAST) {
    if (t < 64) {
      int idx = 0;
#pragma unroll
      for (int q = 0; q < 20; ++q) {
        int i = q / 5, j = q % 5;
        int pos = (j == 0) ? (11 - i)
                 : (j == 1) ? (7 - i)
                 : (j == 2) ? (3 - i)
                 : (j == 3) ? (19 - i)
                            : (15 - i);
        idx |= x[t * 20 + q] << pos;
      }
      if (((idx >> 4) & 255) == o) {
        int local = ((idx >> 16) & 15) * 256 + ((idx >> 12) & 15) * 16 +
                    (idx & 15);
        out[t] = s[PAD(local)];
      }
    }
  } else {
#pragma unroll
    for (int i = 0; i < 2; ++i) {
      int f = (i * 512 + t) * 4;
      int addr = (f >> 8) * 65536 + ((f >> 4) & 15) * 4096 + o * 16 + (f & 15);
      *(float4*)(psi + addr) = *(const float4*)(s + PAD(f));
    }
  }
}

// ---------------------------------------------------------------------------
extern "C" void kernel_launch(void* const* d_in, const int* in_sizes, int n_in,
                              void* d_out, int out_size, void* d_ws, size_t ws_size,
                              hipStream_t stream) {
  const int* x = (const int*)d_in[0];
  const float* peps = (const float*)d_in[1];
  const float* gate = (const float*)d_in[2];
  float* ws = (float*)d_ws;
  float* psi = ws + PSIO;  // gate layout from k_psi0 onward
  float* out = (float*)d_out;

  k_build_cols<<<386, 256, 0, stream>>>(peps, ws);
  k_small<<<320, 256, 0, stream>>>(ws, ws + M01TO, ws + M34TO);
  k_t012<<<256, 256, 0, stream>>>(ws + M01TO, ws + COL2, ws + T12TO);
  k_psi0<<<256, 256, 0, stream>>>(ws + T12TO, ws + M34TO, psi);

  for (int it = 0; it < 5; ++it) {
    k_P1<<<256, 512, 0, stream>>>(psi, gate);
    if (it < 4)
      k_P2<false><<<256, 512, 0, stream>>>(psi, gate, x, out);
    else
      k_P2<true><<<256, 512, 0, stream>>>(psi, gate, x, out);
  }
}